// Round 1
// baseline (714.128 us; speedup 1.0000x reference)
//
#include <hip/hip_runtime.h>

// Sinkhorn-Knopp, log-space, on (64, 1024, 1024) fp32.
// State is always logits - u_i - v_j, so we only carry u, v (64x1024 each).
// Per iteration (fused single pass over logits):
//   u_k[i] = LSE_j(logits[i,j] - v_{k-1}[j])      (wave-local row reduce)
//   colsum[j] += sum_i exp(logits[i,j] - u_k[i])  (fused col accumulation)
// then tiny kernel: v_k = log(colsum), colsum = 0.
// Final: out = exp(logits - u5 - v5).

constexpr int BATCH = 64;
constexpr int N = 1024;
constexpr int ROWS_PER_WAVE = 16;
constexpr int WAVES_PER_WG = 4;
// total rows = 65536; rows per WG = 64 -> 1024 WGs
constexpr int PASS_BLOCKS = (BATCH * N) / (ROWS_PER_WAVE * WAVES_PER_WG);
constexpr int FINAL_BLOCKS = 16384;  // 16384*256 threads * 4 float4 = 64M floats

__global__ __launch_bounds__(256) void init_ws_kernel(float* __restrict__ v,
                                                      float* __restrict__ colsum) {
    int t = blockIdx.x * blockDim.x + threadIdx.x;  // 65536 threads
    v[t] = 0.0f;
    colsum[t] = 0.0f;
}

__global__ __launch_bounds__(256) void sinkhorn_pass_kernel(
    const float* __restrict__ logits, const float* __restrict__ v,
    float* __restrict__ u, float* __restrict__ colsum) {
    __shared__ float lds[WAVES_PER_WG * N];  // 16 KiB

    const int tid = threadIdx.x;
    const int lane = tid & 63;
    const int wid = tid >> 6;
    const int wave_g = blockIdx.x * WAVES_PER_WG + wid;
    const int row0 = wave_g * ROWS_PER_WAVE;  // 16 consecutive rows, same batch
    const int b = row0 >> 10;

    // v for this batch, cached in registers: vr[c] covers j = c*256 + lane*4 + {0..3}
    const float4* vb = reinterpret_cast<const float4*>(v + (b << 10));
    float4 vr[4];
#pragma unroll
    for (int c = 0; c < 4; ++c) vr[c] = vb[c * 64 + lane];

    float4 acc[4];
#pragma unroll
    for (int c = 0; c < 4; ++c) acc[c] = make_float4(0.f, 0.f, 0.f, 0.f);

    const float4* lb =
        reinterpret_cast<const float4*>(logits) + (size_t)row0 * (N / 4) + lane;

    for (int ii = 0; ii < ROWS_PER_WAVE; ++ii) {
        float4 x[4];
#pragma unroll
        for (int c = 0; c < 4; ++c) x[c] = lb[ii * (N / 4) + c * 64];
#pragma unroll
        for (int c = 0; c < 4; ++c) {
            x[c].x -= vr[c].x;
            x[c].y -= vr[c].y;
            x[c].z -= vr[c].z;
            x[c].w -= vr[c].w;
        }
        // row max (16 local + 6-step butterfly over 64 lanes)
        float m = x[0].x;
#pragma unroll
        for (int c = 0; c < 4; ++c) {
            m = fmaxf(m, x[c].x);
            m = fmaxf(m, x[c].y);
            m = fmaxf(m, x[c].z);
            m = fmaxf(m, x[c].w);
        }
#pragma unroll
        for (int off = 32; off >= 1; off >>= 1) m = fmaxf(m, __shfl_xor(m, off));
        // t = exp(x - m) (overwrite x), row sum
        float s = 0.f;
#pragma unroll
        for (int c = 0; c < 4; ++c) {
            x[c].x = __expf(x[c].x - m); s += x[c].x;
            x[c].y = __expf(x[c].y - m); s += x[c].y;
            x[c].z = __expf(x[c].z - m); s += x[c].z;
            x[c].w = __expf(x[c].w - m); s += x[c].w;
        }
#pragma unroll
        for (int off = 32; off >= 1; off >>= 1) s += __shfl_xor(s, off);
        // u' = LSE_j(logits - v) = m + log(s)
        if (lane == 0) u[row0 + ii] = m + __logf(s);
        // column contribution: exp(logits - u') = t/s * exp(v). exp(v) hoisted.
        const float rinv = __builtin_amdgcn_rcpf(s);
#pragma unroll
        for (int c = 0; c < 4; ++c) {
            acc[c].x = fmaf(x[c].x, rinv, acc[c].x);
            acc[c].y = fmaf(x[c].y, rinv, acc[c].y);
            acc[c].z = fmaf(x[c].z, rinv, acc[c].z);
            acc[c].w = fmaf(x[c].w, rinv, acc[c].w);
        }
    }
    // apply the hoisted exp(v) scale
#pragma unroll
    for (int c = 0; c < 4; ++c) {
        acc[c].x *= __expf(vr[c].x);
        acc[c].y *= __expf(vr[c].y);
        acc[c].z *= __expf(vr[c].z);
        acc[c].w *= __expf(vr[c].w);
    }
    // wave partials -> LDS, reduce across the 4 waves, one atomic per element
    float4* lw = reinterpret_cast<float4*>(lds + wid * N);
#pragma unroll
    for (int c = 0; c < 4; ++c) lw[c * 64 + lane] = acc[c];
    __syncthreads();

    const int j0 = tid * 4;  // 256 threads x 4 = 1024 columns
    float4 s0 = *reinterpret_cast<const float4*>(lds + 0 * N + j0);
    const float4 s1 = *reinterpret_cast<const float4*>(lds + 1 * N + j0);
    const float4 s2 = *reinterpret_cast<const float4*>(lds + 2 * N + j0);
    const float4 s3 = *reinterpret_cast<const float4*>(lds + 3 * N + j0);
    s0.x += s1.x + s2.x + s3.x;
    s0.y += s1.y + s2.y + s3.y;
    s0.z += s1.z + s2.z + s3.z;
    s0.w += s1.w + s2.w + s3.w;
    float* dst = colsum + (b << 10) + j0;
    atomicAdd(dst + 0, s0.x);
    atomicAdd(dst + 1, s0.y);
    atomicAdd(dst + 2, s0.z);
    atomicAdd(dst + 3, s0.w);
}

__global__ __launch_bounds__(256) void finalize_kernel(float* __restrict__ colsum,
                                                       float* __restrict__ v) {
    int t = blockIdx.x * blockDim.x + threadIdx.x;  // 65536 threads
    v[t] = __logf(colsum[t]);
    colsum[t] = 0.0f;  // reset for the next pass
}

__global__ __launch_bounds__(256) void final_kernel(const float* __restrict__ logits,
                                                    const float* __restrict__ u,
                                                    const float* __restrict__ v,
                                                    float* __restrict__ out) {
    const int g0 = blockIdx.x * 256 + threadIdx.x;
#pragma unroll
    for (int p = 0; p < 4; ++p) {
        const int g = g0 + p * (FINAL_BLOCKS * 256);  // float4 index < 16777216
        const int e = g << 2;                         // element index < 2^27
        const int r = e >> 10;
        const int jc = e & 1023;
        const int b = r >> 10;
        const float ur = u[r];
        const float4 vv = *reinterpret_cast<const float4*>(v + (b << 10) + jc);
        const float4 x = *reinterpret_cast<const float4*>(logits + (size_t)e);
        float4 o;
        o.x = __expf(x.x - ur - vv.x);
        o.y = __expf(x.y - ur - vv.y);
        o.z = __expf(x.z - ur - vv.z);
        o.w = __expf(x.w - ur - vv.w);
        *reinterpret_cast<float4*>(out + (size_t)e) = o;
    }
}

extern "C" void kernel_launch(void* const* d_in, const int* in_sizes, int n_in,
                              void* d_out, int out_size, void* d_ws, size_t ws_size,
                              hipStream_t stream) {
    const float* logits = (const float*)d_in[0];
    float* out = (float*)d_out;
    float* ws = (float*)d_ws;
    float* u = ws;                  // 65536 floats
    float* v = ws + 65536;          // 65536 floats
    float* colsum = ws + 131072;    // 65536 floats (768 KiB total)

    init_ws_kernel<<<256, 256, 0, stream>>>(v, colsum);
    for (int it = 0; it < 5; ++it) {
        sinkhorn_pass_kernel<<<PASS_BLOCKS, 256, 0, stream>>>(logits, v, u, colsum);
        finalize_kernel<<<256, 256, 0, stream>>>(colsum, v);
    }
    final_kernel<<<FINAL_BLOCKS, 256, 0, stream>>>(logits, u, v, out);
}